// Round 1
// baseline (781.540 us; speedup 1.0000x reference)
//
#include <hip/hip_runtime.h>

// EquivariantLayerNorm: N rows of DIM=480 fp32.
//  [0,128)   : standard LayerNorm over 128 with weight+bias
//  [128,320) : 64 segments x 3, per-segment mean/var norm (no affine)
//  [320,480) : 32 segments x 5, per-segment mean/var norm (no affine)
//
// One 64-lane wave per row; 4 waves (rows) per 256-thread block.
// All global traffic is staged through a per-wave LDS row buffer so every
// HBM access is a coalesced dwordx4 (the previous version moved 73% of the
// bytes through stride-3/stride-5 scalar dword accesses with half-idle lanes
// in the v2 section).

constexpr int N_ROWS = 262144;
constexpr int S = 128;
constexpr int MUL1 = 64, D1 = 3;
constexpr int MUL2 = 32, D2 = 5;
constexpr int DIM = S + MUL1 * D1 + MUL2 * D2; // 480
constexpr int DIMV4 = DIM / 4;                 // 120 float4 per row
constexpr float EPS = 1e-5f;

__global__ __launch_bounds__(256) void eqln_kernel(
    const float* __restrict__ x,
    const float* __restrict__ weight,
    const float* __restrict__ bias,
    float* __restrict__ out)
{
    // Per-wave row buffer: 4 waves x 480 floats = 7680 B. Conflict audit:
    // staging/store: ds_*_b128 lane-consecutive (canonical, conflict-free);
    // scal: b64 stride-2 -> 2-way (free, m136); v1 stride-3, v2 stride-5:
    // coprime to 32 banks -> <=2-way across wave halves (free).
    __shared__ float lds[4][DIM];

    const int wave = threadIdx.x >> 6;   // 0..3 (row within block)
    const int lane = threadIdx.x & 63;
    const long long row = (long long)blockIdx.x * 4 + wave;

    const float4* __restrict__ gin  = (const float4*)(x   + row * DIM);
    float4* __restrict__       gout = (float4*)      (out + row * DIM);
    float* ls = lds[wave];
    float4* lv = (float4*)ls;

    // ---- stage row into LDS: 120 float4, fully coalesced ----
    const bool tail = lane < (DIMV4 - 64);   // lanes 0..55 carry the 2nd chunk
    float4 t0 = gin[lane];
    float4 t1;
    if (tail) t1 = gin[64 + lane];
    lv[lane] = t0;
    if (tail) lv[64 + lane] = t1;

    __syncthreads();

    // ---- scalar LayerNorm over [0,128): lane i owns elements [2i, 2i+1] ----
    float2 v = *(const float2*)(ls + 2 * lane);
    float s  = v.x + v.y;
    float sq = v.x * v.x + v.y * v.y;
#pragma unroll
    for (int off = 32; off >= 1; off >>= 1) {
        s  += __shfl_xor(s,  off, 64);
        sq += __shfl_xor(sq, off, 64);
    }
    const float m   = s * (1.0f / 128.0f);
    const float var = sq * (1.0f / 128.0f) - m * m;
    const float r   = rsqrtf(var + EPS);

    float2 w = *(const float2*)(weight + 2 * lane);
    float2 b = *(const float2*)(bias   + 2 * lane);
    float2 o;
    o.x = (v.x - m) * r * w.x + b.x;
    o.y = (v.y - m) * r * w.y + b.y;
    *(float2*)(ls + 2 * lane) = o;

    // ---- v1: 64 segments of 3 (lane i = segment i), in-place in LDS ----
    {
        float* p = ls + S + 3 * lane;
        float a0 = p[0], a1 = p[1], a2 = p[2];
        float mm = (a0 + a1 + a2) * (1.0f / 3.0f);
        float d0 = a0 - mm, d1 = a1 - mm, d2 = a2 - mm;
        float vv = (d0 * d0 + d1 * d1 + d2 * d2) * (1.0f / 3.0f);
        float rr = rsqrtf(vv + EPS);
        p[0] = d0 * rr;
        p[1] = d1 * rr;
        p[2] = d2 * rr;
    }

    // ---- v2: 32 segments of 5 (lanes 0..31), in-place in LDS ----
    if (lane < 32) {
        float* p = ls + S + MUL1 * D1 + 5 * lane;
        float a[5];
#pragma unroll
        for (int i = 0; i < 5; ++i) a[i] = p[i];
        float ssum = 0.0f;
#pragma unroll
        for (int i = 0; i < 5; ++i) ssum += a[i];
        float mm = ssum * 0.2f;
        float vv = 0.0f;
#pragma unroll
        for (int i = 0; i < 5; ++i) { float d = a[i] - mm; vv += d * d; }
        vv *= 0.2f;
        float rr = rsqrtf(vv + EPS);
#pragma unroll
        for (int i = 0; i < 5; ++i) p[i] = (a[i] - mm) * rr;
    }

    __syncthreads();

    // ---- store row: 120 float4, fully coalesced ----
    gout[lane] = lv[lane];
    if (tail) gout[64 + lane] = lv[64 + lane];
}

extern "C" void kernel_launch(void* const* d_in, const int* in_sizes, int n_in,
                              void* d_out, int out_size, void* d_ws, size_t ws_size,
                              hipStream_t stream) {
    const float* x      = (const float*)d_in[0];
    const float* weight = (const float*)d_in[1];
    const float* bias   = (const float*)d_in[2];
    float* out = (float*)d_out;

    const int rows_per_block = 4;
    dim3 grid(N_ROWS / rows_per_block);  // 65536
    dim3 block(256);
    eqln_kernel<<<grid, block, 0, stream>>>(x, weight, bias, out);
}